// Round 1
// 332.098 us; speedup vs baseline: 1.4250x; 1.4250x over previous
//
#include <hip/hip_runtime.h>
#include <hip/hip_bf16.h>
#include <stdint.h>

// Problem constants
#define M_ROWS 32768
#define N_CODES 8192
#define K_DIM 256
#define NSLICE 32            // N_CODES / BN (BN=256)
#define MARGIN 0.25f         // coarse-key uncertainty window
#define MAXCAND 2560

// Coarse GEMM tile config: 256x256, 8 waves (4x2), BK=64, double-buffered LDS
#define BM 256
#define BN 256

typedef _Float16 half8 __attribute__((ext_vector_type(8)));
typedef _Float16 h4v __attribute__((ext_vector_type(4)));
typedef float f4v __attribute__((ext_vector_type(4)));
typedef float f32x4 __attribute__((ext_vector_type(4)));
typedef __attribute__((address_space(3))) void lds_void;
typedef const __attribute__((address_space(1))) void gbl_cvoid;

// Monotone map: fp32 bits -> uint32 preserving < order (handles sign)
__device__ __forceinline__ unsigned mono32(float f) {
    unsigned u = __float_as_uint(f);
    return (u & 0x80000000u) ? ~u : (u | 0x80000000u);
}
__device__ __forceinline__ unsigned long long pack_key(float d, unsigned col) {
    return ((unsigned long long)mono32(d) << 32) | (unsigned long long)col;
}
__device__ __forceinline__ float unpack_key(unsigned long long k) {
    unsigned m = (unsigned)(k >> 32);
    unsigned u = (m & 0x80000000u) ? (m & 0x7fffffffu) : ~m;
    return __uint_as_float(u);
}
// 2-min pair merge: (b1,b2) <- two smallest of {b1,b2,o1,o2}
__device__ __forceinline__ void merge2(unsigned long long& b1, unsigned long long& b2,
                                       unsigned long long o1, unsigned long long o2) {
    unsigned long long n1 = b1 < o1 ? b1 : o1;
    unsigned long long hi = b1 < o1 ? o1 : b1;
    unsigned long long l2 = b2 < o2 ? b2 : o2;
    b2 = hi < l2 ? hi : l2;
    b1 = n1;
}

// ---------------- prep: z -> f16, MFMA-fragment-tiled --------------------
// Layout: entry e in [0, (M/16)*8*64): ln=e&63, kcg=(e>>6)&7, R=e>>9.
//   Aq[e*16B] = A[R*16 + (ln&15)][kcg*32 + (ln>>4)*8 .. +7]  (8 halfs)
// So each 1KB chunk (R,kcg) is one 16-row x 32-K fragment tile in MFMA
// lane order: global_load_lds dst = base + lane*16 (linear), and
// ds_read_b128 at frag_base + lane*16 is conflict-free.
__global__ __launch_bounds__(256) void prep_zh(const float* __restrict__ z,
                                               _Float16* __restrict__ Aq) {
    int e = blockIdx.x * 256 + threadIdx.x;          // grid 4096 -> 1,048,576
    int ln = e & 63, kcg = (e >> 6) & 7, R = e >> 9;
    int row = R * 16 + (ln & 15);
    int k = kcg * 32 + (ln >> 4) * 8;
    const f4v* src = (const f4v*)(z + (size_t)row * K_DIM + k);
    f4v v0 = src[0], v1 = src[1];
    half8 h;
    #pragma unroll
    for (int j = 0; j < 4; ++j) h[j] = (_Float16)v0[j];
    #pragma unroll
    for (int j = 0; j < 4; ++j) h[4 + j] = (_Float16)v1[j];
    *(half8*)(Aq + (size_t)e * 8) = h;
}

// ---------------- prep: codebook -> f16 tiled (same layout) ------------------
__global__ __launch_bounds__(256) void prep_bt(const float* __restrict__ cb,
                                               _Float16* __restrict__ Bq) {
    int e = blockIdx.x * 256 + threadIdx.x;          // grid 1024 -> 262,144
    int ln = e & 63, kcg = (e >> 6) & 7, C = e >> 9;
    int code = C * 16 + (ln & 15);
    int k = kcg * 32 + (ln >> 4) * 8;
    const f4v* src = (const f4v*)(cb + (size_t)code * K_DIM + k);
    f4v v0 = src[0], v1 = src[1];
    half8 h;
    #pragma unroll
    for (int j = 0; j < 4; ++j) h[j] = (_Float16)v0[j];
    #pragma unroll
    for (int j = 0; j < 4; ++j) h[4 + j] = (_Float16)v1[j];
    *(half8*)(Bq + (size_t)e * 8) = h;
}

// ---------------- prep: esq (fp32 row sumsq of codebook) ---------------------
__global__ __launch_bounds__(256) void prep_esq(const float* __restrict__ cb,
                                                float* __restrict__ esq) {
    int wave = threadIdx.x >> 6, lane = threadIdx.x & 63;
    int row = blockIdx.x * 4 + wave;                 // grid = 2048
    f4v v = *(const f4v*)(cb + (size_t)row * K_DIM + lane * 4);
    float sq = v[0] * v[0] + v[1] * v[1] + v[2] * v[2] + v[3] * v[3];
    #pragma unroll
    for (int m = 32; m; m >>= 1) sq += __shfl_xor(sq, m);
    if (lane == 0) esq[row] = sq;
}

// ---------------- coarse GEMM (256x256) + fused packed-u32 2-min -------------
// key = esq - 2*(zh.eh) + 1024  (zsq dropped: row-constant; +1024 makes keys
// provably positive since true d2 = key - 1024 + zsq >= 0 and zsq <= ~370,
// so raw fp32 bits are order-monotone). Low 7 mantissa bits replaced by the
// local column (ni*16 + l15): trunc error <= 2^-5 ~= 0.03 << MARGIN.
__global__ __launch_bounds__(512) void coarse_gemm(
        const _Float16* __restrict__ Aq, const _Float16* __restrict__ Bq,
        const float* __restrict__ esq, ulonglong2* __restrict__ slices) {
    __shared__ __align__(16) char smem[131072];      // 2 x (A 32KB | B 32KB)
    uint2 (*red)[2] = (uint2(*)[2])smem;             // 4KB alias (post-loop)

    int bid = blockIdx.x;
    int bn = bid & 31;                               // 32 panels: per-XCD L2 reuse
    int bm = bid >> 5;                               // 128 row-tiles
    int m0 = bm * BM, n0 = bn * BN;

    int t = threadIdx.x;
    int lane = t & 63, wave = t >> 6;
    int l15 = lane & 15, quad = lane >> 4;
    int wr = wave >> 1, wc = wave & 1;               // 4x2 wave grid: 64r x 128c

    // prologue: per-lane column keys and adjusted esq (reused all K-steps)
    float es_adj[8];
    unsigned colb[8];
    #pragma unroll
    for (int ni = 0; ni < 8; ++ni) {
        es_adj[ni] = esq[n0 + wc * 128 + ni * 16 + l15] + 1024.0f;
        colb[ni] = (unsigned)(ni * 16 + l15);
    }

    f32x4 acc[4][8] = {};

    const char* Ab = (const char*)Aq + (size_t)bm * 131072;   // 16 RB x 8KB
    const char* Bb = (const char*)Bq + (size_t)bn * 131072;

    // stage one BK=64 K-step (A 32KB + B 32KB) into buffer buf.
    // LDS entry e=(RB*2+kc)*64+ln at e*16; global at (RB*8+ks*2+kc)*1024+ln*16.
    auto stage = [&](int ks, int buf) {
        char* As = smem + buf * 65536;
        char* Bs = As + 32768;
        #pragma unroll
        for (int i = 0; i < 4; ++i) {
            int e = i * 512 + t;
            int RB = e >> 7, kc = (e >> 6) & 1, ln = e & 63;
            size_t goff = ((size_t)(RB * 8 + ks * 2 + kc) << 10) + (size_t)ln * 16;
            __builtin_amdgcn_global_load_lds((gbl_cvoid*)(Ab + goff),
                                             (lds_void*)(As + e * 16), 16, 0, 0);
            __builtin_amdgcn_global_load_lds((gbl_cvoid*)(Bb + goff),
                                             (lds_void*)(Bs + e * 16), 16, 0, 0);
        }
    };

    auto compute = [&](int buf) {
        const char* As = smem + buf * 65536;
        const char* Bs = As + 32768;
        #pragma unroll
        for (int kc = 0; kc < 2; ++kc) {
            half8 a[4], b[8];
            #pragma unroll
            for (int mi = 0; mi < 4; ++mi) {
                int RB = wr * 4 + mi;
                a[mi] = *(const half8*)(As + ((RB * 2 + kc) * 64 + lane) * 16);
            }
            #pragma unroll
            for (int ni = 0; ni < 8; ++ni) {
                int CB = wc * 8 + ni;
                b[ni] = *(const half8*)(Bs + ((CB * 2 + kc) * 64 + lane) * 16);
            }
            #pragma unroll
            for (int mi = 0; mi < 4; ++mi)
                #pragma unroll
                for (int ni = 0; ni < 8; ++ni)
                    acc[mi][ni] = __builtin_amdgcn_mfma_f32_16x16x32_f16(
                        a[mi], b[ni], acc[mi][ni], 0, 0, 0);
        }
    };

    // T3 minimum 2-phase: issue next stage, compute current, one barrier.
    stage(0, 0);
    __syncthreads();
    #pragma unroll
    for (int ks = 0; ks < 4; ++ks) {
        if (ks < 3) stage(ks + 1, (ks + 1) & 1);
        compute(ks & 1);
        __syncthreads();
    }

    // Epilogue: packed-u32 2-min (4-5 VALU/element), 32-bit shuffle tree.
    #pragma unroll
    for (int mi = 0; mi < 4; ++mi) {
        #pragma unroll
        for (int r = 0; r < 4; ++r) {
            unsigned b1 = 0xFFFFFFFFu, b2 = 0xFFFFFFFFu;
            #pragma unroll
            for (int ni = 0; ni < 8; ++ni) {
                float key = fmaf(-2.0f, acc[mi][ni][r], es_adj[ni]);
                unsigned kb = (__float_as_uint(key) & 0xFFFFFF80u) | colb[ni];
                unsigned hi = kb > b1 ? kb : b1;
                b1 = kb < b1 ? kb : b1;
                b2 = hi < b2 ? hi : b2;
            }
            #pragma unroll
            for (int m = 1; m < 16; m <<= 1) {
                unsigned o1 = (unsigned)__shfl_xor((int)b1, m);
                unsigned o2 = (unsigned)__shfl_xor((int)b2, m);
                unsigned hi = b1 > o1 ? b1 : o1;
                b1 = b1 < o1 ? b1 : o1;
                unsigned l2 = b2 < o2 ? b2 : o2;
                b2 = hi < l2 ? hi : l2;
            }
            if (l15 == 0) {
                int rowl = wr * 64 + mi * 16 + quad * 4 + r;
                red[rowl][wc] = make_uint2(b1, b2);
            }
        }
    }
    __syncthreads();
    if (t < 256) {
        uint2 p0 = red[t][0], p1 = red[t][1];
        unsigned m1 = p0.x < p1.x ? p0.x : p1.x;
        unsigned hi = p0.x < p1.x ? p1.x : p0.x;
        unsigned sel = p1.x < p0.x ? 1u : 0u;
        unsigned l2 = p0.y < p1.y ? p0.y : p1.y;
        unsigned m2 = hi < l2 ? hi : l2;
        unsigned col = (unsigned)n0 + sel * 128u + (m1 & 127u);
        // keys positive -> mono32 = bits | 0x80000000; low key bits zeroed.
        unsigned long long q1 =
            ((unsigned long long)((m1 & 0xFFFFFF80u) | 0x80000000u) << 32) | col;
        unsigned long long q2 =
            ((unsigned long long)((m2 & 0xFFFFFF80u) | 0x80000000u) << 32) |
            0xFFFFFFFFull;
        slices[(size_t)(m0 + t) * NSLICE + bn] = make_ulonglong2(q1, q2);
    }
}

// ---------------- merge slices -> bestidx + flag + compacted list -----------
__global__ __launch_bounds__(256) void merge_slices(
        const ulonglong2* __restrict__ slices,
        int* __restrict__ bestidx, int* __restrict__ flags,
        int* __restrict__ list, int* __restrict__ count) {
    int t = threadIdx.x;
    int wave = t >> 6, lane = t & 63;
    int half = lane >> 5, idx = lane & 31;
    int row = blockIdx.x * 8 + wave * 2 + half;      // grid = 4096
    ulonglong2 p = slices[(size_t)row * NSLICE + idx];
    unsigned long long b1 = p.x, b2 = p.y;
    #pragma unroll
    for (int m = 1; m < 32; m <<= 1) {               // within 32-lane halves
        unsigned long long o1 = (unsigned long long)__shfl_xor((long long)b1, m);
        unsigned long long o2 = (unsigned long long)__shfl_xor((long long)b2, m);
        merge2(b1, b2, o1, o2);
    }
    if (idx == 0) {
        bestidx[row] = (int)(unsigned)(b1 & 0xFFFFFFFFULL);
        int f = (unpack_key(b2) - unpack_key(b1) <= MARGIN) ? 1 : 0;
        flags[row] = f;
        if (f) { int pos = atomicAdd(count, 1); list[pos] = row; }
    }
}

// ---------------- refine: exact fp64 over candidate set only ----------------
__global__ __launch_bounds__(256) void refine(
        const float* __restrict__ z, const float* __restrict__ cb,
        const ulonglong2* __restrict__ slices,
        const int* __restrict__ list, const int* __restrict__ count,
        int* __restrict__ bestidx) {
    __shared__ float zrow[K_DIM];
    __shared__ int cand[MAXCAND];
    __shared__ int ncand_s;
    __shared__ unsigned long long sb1;
    __shared__ double wd[4];
    __shared__ int wc[4];
    int t = threadIdx.x, lane = t & 63, wave = t >> 6;
    int n = *count;
    #pragma unroll 1
    for (int li = blockIdx.x; li < n; li += 2048) {
        int row = list[li];
        __syncthreads();                             // protect shared reuse
        zrow[t] = z[(size_t)row * K_DIM + t];
        if (t == 0) ncand_s = 0;
        __syncthreads();
        ulonglong2 p = make_ulonglong2(~0ULL, ~0ULL);
        if (wave == 0) {
            if (lane < NSLICE) p = slices[(size_t)row * NSLICE + lane];
            unsigned long long b1 = p.x;
            #pragma unroll
            for (int m = 1; m < 64; m <<= 1) {
                unsigned long long o =
                    (unsigned long long)__shfl_xor((long long)b1, m);
                b1 = o < b1 ? o : b1;
            }
            if (lane == 0) sb1 = b1;
        }
        __syncthreads();
        float thr = unpack_key(sb1) + MARGIN;
        if (wave == 0 && lane < NSLICE) {
            float k1 = unpack_key(p.x), k2 = unpack_key(p.y);
            if (k2 <= thr) {                         // hidden codes possible
                int pos = atomicAdd(&ncand_s, 256);
                if (pos + 256 <= MAXCAND)
                    for (int j = 0; j < 256; ++j) cand[pos + j] = lane * 256 + j;
            } else if (k1 <= thr) {
                int pos = atomicAdd(&ncand_s, 1);
                if (pos < MAXCAND) cand[pos] = (int)(unsigned)(p.x & 0xFFFFFFFFULL);
            }
        }
        __syncthreads();
        int nc = ncand_s;
        bool full = nc > MAXCAND;                    // rigorous fallback
        int total = full ? N_CODES : nc;
        double bd = 1e300;
        int bc = 0x7fffffff;
        #pragma unroll 1
        for (int base = 0; base < total; base += 256) {
            int i = base + t;
            if (i < total) {
                int code = full ? i : cand[i];
                const f4v* e4 = (const f4v*)(cb + (size_t)code * K_DIM);
                double s0 = 0, s1 = 0, s2 = 0, s3 = 0;
                #pragma unroll 4
                for (int k4 = 0; k4 < 64; ++k4) {
                    f4v e = e4[k4];
                    f4v zz = *(const f4v*)&zrow[k4 * 4];
                    float d0 = zz[0] - e[0], d1 = zz[1] - e[1];
                    float d2 = zz[2] - e[2], d3 = zz[3] - e[3];
                    s0 = fma((double)d0, (double)d0, s0);
                    s1 = fma((double)d1, (double)d1, s1);
                    s2 = fma((double)d2, (double)d2, s2);
                    s3 = fma((double)d3, (double)d3, s3);
                }
                double s = (s0 + s1) + (s2 + s3);
                if (s < bd || (s == bd && code < bc)) { bd = s; bc = code; }
            }
        }
        #pragma unroll
        for (int m = 1; m < 64; m <<= 1) {
            double od = __shfl_xor(bd, m);
            int oc = __shfl_xor(bc, m);
            if (od < bd || (od == bd && oc < bc)) { bd = od; bc = oc; }
        }
        if (lane == 0) { wd[wave] = bd; wc[wave] = bc; }
        __syncthreads();
        if (t == 0) {
            #pragma unroll
            for (int w = 1; w < 4; ++w)
                if (wd[w] < bd || (wd[w] == bd && wc[w] < bc)) { bd = wd[w]; bc = wc[w]; }
            bestidx[row] = bc;
        }
    }
}

// ---------------- ws-light fallback (only if ws too small) ------------------
__global__ __launch_bounds__(256) void vq_bruteforce(const float* __restrict__ z,
                                                     const float* __restrict__ cb,
                                                     float* __restrict__ out_idx) {
    __shared__ float As[128 * 16];
    __shared__ float Bs[128 * 16];
    int t = threadIdx.x;
    int tx = t & 15, ty = t >> 4;
    int r0 = blockIdx.x * 128;
    unsigned long long best[8];
    #pragma unroll
    for (int j = 0; j < 8; ++j) best[j] = ~0ULL;

    for (int n0 = 0; n0 < N_CODES; n0 += 128) {
        float acc[8][8] = {};
        for (int k0 = 0; k0 < K_DIM; k0 += 16) {
            __syncthreads();
            int row = t >> 1, c8 = (t & 1) * 8;
            #pragma unroll
            for (int j = 0; j < 8; ++j)
                As[row * 16 + c8 + j] = z[(size_t)(r0 + row) * K_DIM + k0 + c8 + j];
            #pragma unroll
            for (int j = 0; j < 8; ++j)
                Bs[row * 16 + c8 + j] = cb[(size_t)(n0 + row) * K_DIM + k0 + c8 + j];
            __syncthreads();
            #pragma unroll
            for (int k = 0; k < 16; ++k) {
                float a[8], b[8];
                #pragma unroll
                for (int j = 0; j < 8; ++j) a[j] = As[(ty * 8 + j) * 16 + k];
                #pragma unroll
                for (int j = 0; j < 8; ++j) b[j] = Bs[(tx * 8 + j) * 16 + k];
                #pragma unroll
                for (int i = 0; i < 8; ++i)
                    #pragma unroll
                    for (int j = 0; j < 8; ++j) {
                        float d = a[i] - b[j];
                        acc[i][j] += d * d;
                    }
            }
        }
        #pragma unroll
        for (int i = 0; i < 8; ++i) {
            unsigned long long bv = ~0ULL;
            #pragma unroll
            for (int j = 0; j < 8; ++j) {
                unsigned long long p =
                    pack_key(acc[i][j], (unsigned)(n0 + tx * 8 + j));
                bv = (p < bv) ? p : bv;
            }
            #pragma unroll
            for (int m = 1; m < 16; m <<= 1) {
                unsigned long long o =
                    (unsigned long long)__shfl_xor((long long)bv, m);
                bv = (o < bv) ? o : bv;
            }
            if (tx == 0 && bv < best[i]) best[i] = bv;
        }
    }
    if (tx == 0) {
        #pragma unroll
        for (int i = 0; i < 8; ++i)
            out_idx[r0 + ty * 8 + i] =
                (float)(unsigned)(best[i] & 0xFFFFFFFFULL);
    }
}

// ---------------- finalize: gather, straight-through out, loss sum ----------
__global__ __launch_bounds__(256) void finalize(const float* __restrict__ z,
                                                const float* __restrict__ cb,
                                                const int* __restrict__ bestidx,
                                                float* __restrict__ out,
                                                double* __restrict__ accum,
                                                int use_int) {
    int wave = threadIdx.x >> 6, lane = threadIdx.x & 63;
    float* out_idx = out + (size_t)M_ROWS * K_DIM;
    float se = 0.f;
    #pragma unroll 1
    for (int row = blockIdx.x * 4 + wave; row < M_ROWS; row += 1024 * 4) {
        int idx = use_int ? bestidx[row] : (int)out_idx[row];
        f4v zv = *(const f4v*)(z  + (size_t)row * K_DIM + lane * 4);
        f4v qv = *(const f4v*)(cb + (size_t)idx * K_DIM + lane * 4);
        f4v ov;
        #pragma unroll
        for (int j = 0; j < 4; ++j) {
            float d = qv[j] - zv[j];                 // ref: z_q - z_e
            ov[j] = zv[j] + d;                       // ref: z_e + (z_q - z_e)
            se += d * d;
        }
        *(f4v*)(out + (size_t)row * K_DIM + lane * 4) = ov;
        if (lane == 0) out_idx[row] = (float)idx;
    }
    #pragma unroll
    for (int m = 32; m; m >>= 1) se += __shfl_xor(se, m);
    __shared__ float part[4];
    if (lane == 0) part[wave] = se;
    __syncthreads();
    if (threadIdx.x == 0)
        atomicAdd(accum, (double)((part[0] + part[1]) + (part[2] + part[3])));
}

__global__ void write_loss(const double* __restrict__ accum,
                           float* __restrict__ out) {
    // vq_loss = codebook_loss + 0.25*commitment_loss = 1.25 * mean(diff^2)
    out[(size_t)M_ROWS * K_DIM + M_ROWS] =
        (float)(1.25 * (*accum / (double)((size_t)M_ROWS * K_DIM)));
}

// ---------------- launch ----------------------------------------------------
extern "C" void kernel_launch(void* const* d_in, const int* in_sizes, int n_in,
                              void* d_out, int out_size, void* d_ws, size_t ws_size,
                              hipStream_t stream) {
    const float* z  = (const float*)d_in[0];
    const float* cb = (const float*)d_in[1];
    float* out = (float*)d_out;
    float* out_idx = out + (size_t)M_ROWS * K_DIM;

    size_t offA  = 0;                                             // Aq 16 MB
    size_t offBq = offA + (size_t)M_ROWS * K_DIM * 2;             // Bq 4 MB
    size_t offE  = offBq + (size_t)N_CODES * K_DIM * 2;           // esq 32 KB
    size_t offS  = offE + (size_t)N_CODES * 4;                    // slices 16 MB
    size_t offBI = offS + (size_t)M_ROWS * NSLICE * 16;           // bestidx 128 KB
    size_t offF  = offBI + (size_t)M_ROWS * 4;                    // flags 128 KB
    size_t offL  = offF + (size_t)M_ROWS * 4;                     // list 128 KB
    size_t offC  = offL + (size_t)M_ROWS * 4;                     // count 16 B
    size_t offAcc = offC + 16;
    size_t need  = offAcc + 16;

    if (ws_size >= need) {
        _Float16* Aq = (_Float16*)((char*)d_ws + offA);
        _Float16* Bq = (_Float16*)((char*)d_ws + offBq);
        float* esq   = (float*)((char*)d_ws + offE);
        ulonglong2* slices = (ulonglong2*)((char*)d_ws + offS);
        int* bestidx = (int*)((char*)d_ws + offBI);
        int* flags   = (int*)((char*)d_ws + offF);
        int* list    = (int*)((char*)d_ws + offL);
        int* count   = (int*)((char*)d_ws + offC);
        double* accum = (double*)((char*)d_ws + offAcc);

        hipMemsetAsync((char*)d_ws + offC, 0, 32, stream);        // count+accum

        prep_zh<<<(M_ROWS / 16) * 8 * 64 / 256, 256, 0, stream>>>(z, Aq);
        prep_bt<<<(N_CODES / 16) * 8 * 64 / 256, 256, 0, stream>>>(cb, Bq);
        prep_esq<<<N_CODES / 4, 256, 0, stream>>>(cb, esq);
        coarse_gemm<<<(M_ROWS / BM) * (N_CODES / BN), 512, 0, stream>>>(
            Aq, Bq, esq, slices);
        merge_slices<<<M_ROWS / 8, 256, 0, stream>>>(slices, bestidx, flags,
                                                     list, count);
        refine<<<2048, 256, 0, stream>>>(z, cb, slices, list, count, bestidx);
        finalize<<<1024, 256, 0, stream>>>(z, cb, bestidx, out, accum, 1);
        write_loss<<<1, 1, 0, stream>>>(accum, out);
    } else {
        double* accum = (double*)d_ws;
        hipMemsetAsync(d_ws, 0, sizeof(double), stream);
        vq_bruteforce<<<M_ROWS / 128, 256, 0, stream>>>(z, cb, out_idx);
        finalize<<<1024, 256, 0, stream>>>(z, cb, nullptr, out, accum, 0);
        write_loss<<<1, 1, 0, stream>>>(accum, out);
    }
}